// Round 2
// baseline (272.136 us; speedup 1.0000x reference)
//
#include <hip/hip_runtime.h>

#define N_ATOMS 1024
#define N_EDGES 8192
#define NBATCH  256
#define NEG     0.01f

typedef unsigned int u32;

// ---------- bf16 helpers (manual, RNE) ----------
__device__ __forceinline__ float bf_lo(u32 u) { return __uint_as_float(u << 16); }
__device__ __forceinline__ float bf_hi(u32 u) { return __uint_as_float(u & 0xffff0000u); }
__device__ __forceinline__ u32 bf_rne(float f) {
    u32 u = __float_as_uint(f);
    return (u + 0x7fffu + ((u >> 16) & 1u)) >> 16;
}
__device__ __forceinline__ u32 pack_bf(float lo, float hi) {
    return bf_rne(lo) | (bf_rne(hi) << 16);
}

// ---------- workspace layout ----------
#define ROWPTR_OFF 0                       // int[1025] (pad 4352)
#define COLW_OFF   4352                    // int2[8192] = 65536
#define SELFW_OFF  (4352 + 65536)          // float[1024]
#define PERM_OFF   (4352 + 65536 + 4096)   // int[1024]

// ---------- LDS layout of main kernel ----------
#define TSTR 72                               // tile row stride in bf16 (144 B)
#define SM_TILE_BYTES (N_ATOMS * TSTR * 2)    // 147456
#define SM_CT_OFF SM_TILE_BYTES               // ctile: 1024*3 floats = 12288 B
#define SM_TOTAL (SM_TILE_BYTES + 12288)      // 159744 <= 163840

// =====================================================================
// Kernel 1: build CSR (grouped by dst) + norm weights + degree-sorted
// atom permutation. 1 block, amortized cost.
// =====================================================================
__global__ __launch_bounds__(1024) void build_csr(
    const int* __restrict__ ei,          // [2, E]: row0 = src, row1 = dst
    int*  __restrict__ rowptr,           // [1025]
    int2* __restrict__ colw,             // [E]: {src, w_bits}
    float* __restrict__ selfw_g,         // [1024]
    int*  __restrict__ perm_g)           // [1024] degree-sorted atom ids
{
    __shared__ int   sdeg[N_ATOMS];
    __shared__ int   sstart[N_ATOMS];
    __shared__ float sdinv[N_ATOMS];
    __shared__ int   wtot[16];
    __shared__ int   hist[128];
    const int t = threadIdx.x;
    const int lane = t & 63;
    const int w = t >> 6;
    const int* srcA = ei;
    const int* dstA = ei + N_EDGES;

    sdeg[t] = 0;
    if (t < 128) hist[t] = 0;
    __syncthreads();
    for (int e = t; e < N_EDGES; e += 1024) atomicAdd(&sdeg[dstA[e]], 1);
    __syncthreads();

    const int myv = sdeg[t];
    // wave-level inclusive scan
    int v = myv;
    #pragma unroll
    for (int d = 1; d < 64; d <<= 1) {
        int u = __shfl_up(v, d, 64);
        if (lane >= d) v += u;
    }
    if (lane == 63) wtot[w] = v;
    __syncthreads();
    if (t == 0) {
        int run = 0;
        #pragma unroll
        for (int i = 0; i < 16; ++i) { int c = wtot[i]; wtot[i] = run; run += c; }
    }
    __syncthreads();
    const int start = v - myv + wtot[w];
    sstart[t] = start;
    const float dv = rsqrtf((float)myv + 1.0f);
    sdinv[t] = dv;
    rowptr[t] = start;
    if (t == N_ATOMS - 1) rowptr[N_ATOMS] = start + myv;
    selfw_g[t] = dv * dv;

    // degree histogram -> counting-sort permutation
    const int dcl = myv < 127 ? myv : 127;
    atomicAdd(&hist[dcl], 1);
    sdeg[t] = 0;   // reuse as fill counters for colw
    __syncthreads();
    if (t == 0) {
        int run = 0;
        for (int i = 0; i < 128; ++i) { int c = hist[i]; hist[i] = run; run += c; }
    }
    __syncthreads();
    const int pos = atomicAdd(&hist[dcl], 1);
    perm_g[pos] = t;
    __syncthreads();

    for (int e = t; e < N_EDGES; e += 1024) {
        const int d = dstA[e];
        const int s = srcA[e];
        const int slot = atomicAdd(&sdeg[d], 1);
        const float wgt = sdinv[s] * sdinv[d];
        colw[sstart[d] + slot] = make_int2(s, __float_as_int(wgt));
    }
}

// =====================================================================
// Kernel 2: fused GCN x2 + mean-pool + project. 1 block per molecule.
// 512 threads, 2 atoms/thread (degree-sorted assignment).
// =====================================================================
__global__ __launch_bounds__(512, 2) void gnn_main(
    const float* __restrict__ x,
    const int*  __restrict__ rowptr,
    const int2* __restrict__ colw,
    const float* __restrict__ selfw_g,
    const int*  __restrict__ perm_g,
    const float* __restrict__ W1, const float* __restrict__ b1,
    const float* __restrict__ W2, const float* __restrict__ b2,
    const float* __restrict__ Wp, const float* __restrict__ bp,
    float* __restrict__ out)
{
    extern __shared__ char smem[];
    float* ctile = (float*)(smem + SM_CT_OFF);   // [1024*3] coords
    float* wpool = ctile;                        // aliased after phase 1: [8][64]
    float* gvec  = ctile + 512;                  // [64]

    const int t = threadIdx.x;
    const int b = blockIdx.x;
    const float* xb = x + (size_t)b * (3 * N_ATOMS);

    const int atomA = perm_g[t];
    const int atomB = perm_g[t + 512];

    // ---- phase 0: coords -> ctile (coalesced) ----
    #pragma unroll
    for (int i = 0; i < 6; ++i) ctile[t + i * 512] = xb[t + i * 512];
    __syncthreads();

    // ---- phase 1: aggregate coords (3 feats), GEMM1 + leaky -> bf16 tile ----
    #pragma unroll
    for (int a = 0; a < 2; ++a) {
        const int atom = a == 0 ? atomA : atomB;
        const int s0 = rowptr[atom], s1 = rowptr[atom + 1];
        float A0, A1, A2;
        {
            const float sw = selfw_g[atom];
            A0 = sw * ctile[atom * 3 + 0];
            A1 = sw * ctile[atom * 3 + 1];
            A2 = sw * ctile[atom * 3 + 2];
        }
        for (int j = s0; j < s1; ++j) {
            const int2 cw = colw[j];
            const float wt = __int_as_float(cw.y);
            const float* cr = ctile + cw.x * 3;
            A0 += wt * cr[0]; A1 += wt * cr[1]; A2 += wt * cr[2];
        }
        u32* trow = (u32*)(smem + (size_t)atom * (TSTR * 2));
        #pragma unroll
        for (int h = 0; h < 2; ++h) {
            float o[32];
            #pragma unroll
            for (int f = 0; f < 32; ++f) {
                const int fc = h * 32 + f;
                float vv = b1[fc] + A0 * W1[fc] + A1 * W1[64 + fc] + A2 * W1[128 + fc];
                o[f] = fmaxf(vv, NEG * vv);
            }
            #pragma unroll
            for (int p = 0; p < 16; ++p) trow[h * 16 + p] = pack_bf(o[2 * p], o[2 * p + 1]);
        }
    }
    __syncthreads();

    // ---- phase 2+3 fused: per atom, aggregate h1 -> regs, GEMM2 + leaky,
    //      accumulate into pool partial pl[64]. No LDS write-back. ----
    float pl[64];
    #pragma unroll
    for (int f = 0; f < 64; ++f) pl[f] = 0.0f;

    #pragma unroll
    for (int a = 0; a < 2; ++a) {
        const int atom = a == 0 ? atomA : atomB;
        float acc[64];
        #pragma unroll
        for (int f = 0; f < 64; ++f) acc[f] = 0.0f;
        const int s0 = rowptr[atom], s1 = rowptr[atom + 1];
        // j = s0-1 is the self-loop term
        int   c  = atom;
        float wt = selfw_g[atom];
        for (int j = s0 - 1; j < s1; ++j) {
            const uint4* row = (const uint4*)(smem + (size_t)c * (TSTR * 2));
            const float wcur = wt;
            if (j + 1 < s1) {            // prefetch next edge
                const int2 cw = colw[j + 1];
                c = cw.x; wt = __int_as_float(cw.y);
            }
            #pragma unroll
            for (int m = 0; m < 8; ++m) {
                const uint4 q = row[m];
                acc[8*m+0] += wcur * bf_lo(q.x);
                acc[8*m+1] += wcur * bf_hi(q.x);
                acc[8*m+2] += wcur * bf_lo(q.y);
                acc[8*m+3] += wcur * bf_hi(q.y);
                acc[8*m+4] += wcur * bf_lo(q.z);
                acc[8*m+5] += wcur * bf_hi(q.z);
                acc[8*m+6] += wcur * bf_lo(q.w);
                acc[8*m+7] += wcur * bf_hi(q.w);
            }
        }
        // GEMM2 (W2 via uniform scalar loads), leaky, pool-accumulate
        #pragma unroll
        for (int fc = 0; fc < 4; ++fc) {
            float o[16];
            #pragma unroll
            for (int f = 0; f < 16; ++f) o[f] = b2[fc * 16 + f];
            #pragma unroll
            for (int j = 0; j < 64; ++j) {
                const float aj = acc[j];
                const float* wrow = W2 + j * 64 + fc * 16;   // lane-uniform -> s_load
                #pragma unroll
                for (int f = 0; f < 16; ++f) o[f] += aj * wrow[f];
            }
            #pragma unroll
            for (int f = 0; f < 16; ++f) {
                const float vv = o[f];
                pl[fc * 16 + f] += fmaxf(vv, NEG * vv);
            }
        }
    }

    // ---- pool reduce: fold across 64 lanes (63 shfls), lane ends with
    //      feature bitrev6(lane) fully reduced within its wave ----
    #pragma unroll
    for (int s = 0; s < 6; ++s) {
        const int half = 64 >> (s + 1);
        const bool up = (t >> s) & 1;
        #pragma unroll
        for (int i = 0; i < half; ++i) {
            const float mine = up ? pl[i] : pl[i + half];
            const float oth = __shfl_xor(mine, 1 << s, 64);
            pl[i] = (up ? pl[i + half] : pl[i]) + oth;
        }
    }
    {
        const int l = t & 63;
        const int br = ((l & 1) << 5) | ((l & 2) << 3) | ((l & 4) << 1)
                     | ((l & 8) >> 1) | ((l & 16) >> 3) | ((l & 32) >> 5);
        wpool[(t >> 6) * 64 + br] = pl[0];
    }
    __syncthreads();

    if (t < 64) {
        float s = 0.0f;
        #pragma unroll
        for (int w = 0; w < 8; ++w) s += wpool[w * 64 + t];
        gvec[t] = s * (1.0f / 1024.0f);
    }
    __syncthreads();

    // ---- phase 4: project MLP (threads 0..127) ----
    if (t < 128) {
        float s = bp[t];
        #pragma unroll
        for (int f = 0; f < 64; ++f) s += gvec[f] * Wp[f * 128 + t];
        s = fmaxf(s, NEG * s);
        out[(size_t)b * 128 + t] = s;
    }
}

// =====================================================================
extern "C" void kernel_launch(void* const* d_in, const int* in_sizes, int n_in,
                              void* d_out, int out_size, void* d_ws, size_t ws_size,
                              hipStream_t stream) {
    const float* x  = (const float*)d_in[0];
    const int*   ei = (const int*)  d_in[1];
    const float* W1 = (const float*)d_in[2];
    const float* b1 = (const float*)d_in[3];
    const float* W2 = (const float*)d_in[4];
    const float* b2 = (const float*)d_in[5];
    const float* Wp = (const float*)d_in[6];
    const float* bp = (const float*)d_in[7];
    float* out = (float*)d_out;

    char* ws = (char*)d_ws;
    int*   rowptr = (int*)  (ws + ROWPTR_OFF);
    int2*  colw   = (int2*) (ws + COLW_OFF);
    float* selfw  = (float*)(ws + SELFW_OFF);
    int*   perm   = (int*)  (ws + PERM_OFF);

    build_csr<<<1, 1024, 0, stream>>>(ei, rowptr, colw, selfw, perm);

    (void)hipFuncSetAttribute((const void*)gnn_main,
                              hipFuncAttributeMaxDynamicSharedMemorySize, SM_TOTAL);
    gnn_main<<<NBATCH, 512, SM_TOTAL, stream>>>(
        x, rowptr, colw, selfw, perm, W1, b1, W2, b2, Wp, bp, out);
}

// Round 3
// 43.666 us; speedup vs baseline: 6.2322x; 6.2322x over previous
//
#include <hip/hip_runtime.h>

#define N_ATOMS 1024
#define N_EDGES 8192
#define NBATCH  256
#define NEG     0.01f

typedef unsigned int u32;
typedef __attribute__((ext_vector_type(8))) short bf16x8;   // 8 bf16 = 4 VGPRs
typedef __attribute__((ext_vector_type(4))) float f32x4;

// ---------- bf16 helpers (manual, RNE) ----------
__device__ __forceinline__ float bf_lo(u32 u) { return __uint_as_float(u << 16); }
__device__ __forceinline__ float bf_hi(u32 u) { return __uint_as_float(u & 0xffff0000u); }
__device__ __forceinline__ u32 bf_rne(float f) {
    u32 u = __float_as_uint(f);
    return (u + 0x7fffu + ((u >> 16) & 1u)) >> 16;
}
__device__ __forceinline__ u32 pack_bf(float lo, float hi) {
    return bf_rne(lo) | (bf_rne(hi) << 16);
}

// ---------- workspace layout ----------
#define ROWPTR_OFF 0                       // int[1025] (pad 4352)
#define COLW_OFF   4352                    // int2[8192] = 65536
#define SELFW_OFF  (4352 + 65536)          // float[1024]
#define PERM_OFF   (4352 + 65536 + 4096)   // int[1024]

// ---------- LDS layout of main kernel ----------
#define TSTR_B 144                            // tile row stride bytes (72 bf16)
#define SM_TILE_BYTES (N_ATOMS * TSTR_B)      // 147456
#define SM_CT_OFF SM_TILE_BYTES               // ctile: 1024*3 f32 = 12288 B
#define SM_TOTAL (SM_TILE_BYTES + 12288)      // 159744 <= 163840

// =====================================================================
// Kernel 1: build CSR (grouped by dst) + norm weights + degree-sorted
// atom permutation. 1 block, amortized cost.
// =====================================================================
__global__ __launch_bounds__(1024) void build_csr(
    const int* __restrict__ ei,          // [2, E]: row0 = src, row1 = dst
    int*  __restrict__ rowptr,           // [1025]
    int2* __restrict__ colw,             // [E]: {src, w_bits}
    float* __restrict__ selfw_g,         // [1024]
    int*  __restrict__ perm_g)           // [1024] degree-sorted atom ids
{
    __shared__ int   sdeg[N_ATOMS];
    __shared__ int   sstart[N_ATOMS];
    __shared__ float sdinv[N_ATOMS];
    __shared__ int   wtot[16];
    __shared__ int   hist[128];
    const int t = threadIdx.x;
    const int lane = t & 63;
    const int w = t >> 6;
    const int* srcA = ei;
    const int* dstA = ei + N_EDGES;

    sdeg[t] = 0;
    if (t < 128) hist[t] = 0;
    __syncthreads();
    for (int e = t; e < N_EDGES; e += 1024) atomicAdd(&sdeg[dstA[e]], 1);
    __syncthreads();

    const int myv = sdeg[t];
    // wave-level inclusive scan
    int v = myv;
    #pragma unroll
    for (int d = 1; d < 64; d <<= 1) {
        int u = __shfl_up(v, d, 64);
        if (lane >= d) v += u;
    }
    if (lane == 63) wtot[w] = v;
    __syncthreads();
    if (t == 0) {
        int run = 0;
        #pragma unroll
        for (int i = 0; i < 16; ++i) { int c = wtot[i]; wtot[i] = run; run += c; }
    }
    __syncthreads();
    const int start = v - myv + wtot[w];
    sstart[t] = start;
    const float dv = rsqrtf((float)myv + 1.0f);
    sdinv[t] = dv;
    rowptr[t] = start;
    if (t == N_ATOMS - 1) rowptr[N_ATOMS] = start + myv;
    selfw_g[t] = dv * dv;

    // degree histogram -> counting-sort permutation
    const int dcl = myv < 127 ? myv : 127;
    atomicAdd(&hist[dcl], 1);
    sdeg[t] = 0;   // reuse as fill counters for colw
    __syncthreads();
    if (t == 0) {
        int run = 0;
        for (int i = 0; i < 128; ++i) { int c = hist[i]; hist[i] = run; run += c; }
    }
    __syncthreads();
    const int pos = atomicAdd(&hist[dcl], 1);
    perm_g[pos] = t;
    __syncthreads();

    for (int e = t; e < N_EDGES; e += 1024) {
        const int d = dstA[e];
        const int s = srcA[e];
        const int slot = atomicAdd(&sdeg[d], 1);
        const float wgt = sdinv[s] * sdinv[d];
        colw[sstart[d] + slot] = make_int2(s, __float_as_int(wgt));
    }
}

// =====================================================================
// Kernel 2: fused GCN x2 + mean-pool + project. 1 block per molecule.
// 1024 threads, 1 atom per thread (degree-sorted). GEMM2 via MFMA.
// =====================================================================
__global__ __launch_bounds__(1024, 4) void gnn_main(
    const float* __restrict__ x,
    const int*  __restrict__ rowptr,
    const int2* __restrict__ colw,
    const float* __restrict__ selfw_g,
    const int*  __restrict__ perm_g,
    const float* __restrict__ W1, const float* __restrict__ b1,
    const float* __restrict__ W2, const float* __restrict__ b2,
    const float* __restrict__ Wp, const float* __restrict__ bp,
    float* __restrict__ out)
{
    extern __shared__ char smem[];
    float* ctile = (float*)(smem + SM_CT_OFF);   // [1024*3] coords (phase 0/1)
    float* wpool = ctile;                        // aliased in phase 3: [16][64]
    float* gvec  = ctile + 1024;                 // [64]

    const int t = threadIdx.x;
    const int b = blockIdx.x;
    const float* xb = x + (size_t)b * (3 * N_ATOMS);

    const int atom = perm_g[t];
    const int s0 = rowptr[atom], s1 = rowptr[atom + 1];
    const float sw = selfw_g[atom];

    // ---- phase 0: coords -> ctile (coalesced) ----
    #pragma unroll
    for (int i = 0; i < 3; ++i) ctile[t + i * 1024] = xb[t + i * 1024];
    __syncthreads();

    // ---- phase 1: aggregate coords (3 feats), GEMM1 + leaky -> bf16 tile ----
    {
        float A0 = sw * ctile[atom * 3 + 0];
        float A1 = sw * ctile[atom * 3 + 1];
        float A2 = sw * ctile[atom * 3 + 2];
        for (int j = s0; j < s1; ++j) {
            const int2 cw = colw[j];
            const float wt = __int_as_float(cw.y);
            const float* cr = ctile + cw.x * 3;
            A0 += wt * cr[0]; A1 += wt * cr[1]; A2 += wt * cr[2];
        }
        uint4* trow = (uint4*)(smem + (size_t)atom * TSTR_B);
        #pragma unroll
        for (int q = 0; q < 4; ++q) {
            float o[16];
            #pragma unroll
            for (int f = 0; f < 16; ++f) {
                const int fc = q * 16 + f;
                float vv = b1[fc] + A0 * W1[fc] + A1 * W1[64 + fc] + A2 * W1[128 + fc];
                o[f] = fmaxf(vv, NEG * vv);
            }
            uint4 p0, p1;
            p0.x = pack_bf(o[0],  o[1]);  p0.y = pack_bf(o[2],  o[3]);
            p0.z = pack_bf(o[4],  o[5]);  p0.w = pack_bf(o[6],  o[7]);
            p1.x = pack_bf(o[8],  o[9]);  p1.y = pack_bf(o[10], o[11]);
            p1.z = pack_bf(o[12], o[13]); p1.w = pack_bf(o[14], o[15]);
            trow[q * 2]     = p0;
            trow[q * 2 + 1] = p1;
        }
    }
    __syncthreads();

    // ---- phase 2: aggregate h1 over edges (bf16 tile -> fp32 regs) ----
    float acc[64];
    {
        #pragma unroll
        for (int f = 0; f < 64; ++f) acc[f] = 0.0f;
        int   c  = atom;                // j = s0-1 is the self-loop term
        float wt = sw;
        for (int j = s0 - 1; j < s1; ++j) {
            const uint4* row = (const uint4*)(smem + (size_t)c * TSTR_B);
            const float wcur = wt;
            if (j + 1 < s1) {           // prefetch next edge
                const int2 cw = colw[j + 1];
                c = cw.x; wt = __int_as_float(cw.y);
            }
            #pragma unroll
            for (int m = 0; m < 8; ++m) {
                const uint4 q = row[m];
                acc[8*m+0] += wcur * bf_lo(q.x);
                acc[8*m+1] += wcur * bf_hi(q.x);
                acc[8*m+2] += wcur * bf_lo(q.y);
                acc[8*m+3] += wcur * bf_hi(q.y);
                acc[8*m+4] += wcur * bf_lo(q.z);
                acc[8*m+5] += wcur * bf_hi(q.z);
                acc[8*m+6] += wcur * bf_lo(q.w);
                acc[8*m+7] += wcur * bf_hi(q.w);
            }
        }
    }
    __syncthreads();    // everyone done READING the tile

    // write aggregated row back (bf16) to own tile row
    {
        uint4* trow = (uint4*)(smem + (size_t)atom * TSTR_B);
        #pragma unroll
        for (int q = 0; q < 8; ++q) {
            uint4 p;
            p.x = pack_bf(acc[8*q+0], acc[8*q+1]);
            p.y = pack_bf(acc[8*q+2], acc[8*q+3]);
            p.z = pack_bf(acc[8*q+4], acc[8*q+5]);
            p.w = pack_bf(acc[8*q+6], acc[8*q+7]);
            trow[q] = p;
        }
    }
    __syncthreads();

    // ---- phase 3: GEMM2 via MFMA (16x16x32 bf16) + bias + leaky + pool ----
    // Wave w handles atoms [w*64, w*64+64) as 4 row-tiles of 16.
    // A[row][k]: row = lane&15, k = (lane>>4)*8 + j (per 32-wide K step).
    // B[k][col]: col = lane&15, same k mapping. C/D: col=lane&15,
    // row=(lane>>4)*4+reg (m89-verified).
    {
        const int l15 = t & 15;
        const int lq  = (t & 63) >> 4;
        const int w   = t >> 6;

        // W2 fragments: wf[kt][ct], k = kt*32 + lq*8 + j, col = ct*16 + l15
        bf16x8 wf[2][4];
        #pragma unroll
        for (int kt = 0; kt < 2; ++kt)
            #pragma unroll
            for (int ct = 0; ct < 4; ++ct)
                #pragma unroll
                for (int j = 0; j < 8; ++j) {
                    const int k = kt * 32 + lq * 8 + j;
                    wf[kt][ct][j] = (short)bf_rne(W2[k * 64 + ct * 16 + l15]);
                }
        float bias[4];
        #pragma unroll
        for (int ct = 0; ct < 4; ++ct) bias[ct] = b2[ct * 16 + l15];

        float pool[4] = {0.f, 0.f, 0.f, 0.f};
        #pragma unroll
        for (int rt = 0; rt < 4; ++rt) {
            const char* abase = smem + (size_t)(w * 64 + rt * 16 + l15) * TSTR_B + lq * 16;
            const bf16x8 a0 = *(const bf16x8*)(abase);       // k = lq*8+j      (kt=0)
            const bf16x8 a1 = *(const bf16x8*)(abase + 64);  // k = 32+lq*8+j   (kt=1)
            #pragma unroll
            for (int ct = 0; ct < 4; ++ct) {
                f32x4 cf = {0.f, 0.f, 0.f, 0.f};
                cf = __builtin_amdgcn_mfma_f32_16x16x32_bf16(a0, wf[0][ct], cf, 0, 0, 0);
                cf = __builtin_amdgcn_mfma_f32_16x16x32_bf16(a1, wf[1][ct], cf, 0, 0, 0);
                float s = 0.0f;
                #pragma unroll
                for (int r = 0; r < 4; ++r) {
                    float vv = cf[r] + bias[ct];
                    s += fmaxf(vv, NEG * vv);
                }
                pool[ct] += s;
            }
        }
        // reduce across the 4 row-groups (lanes differing in bits 4,5)
        #pragma unroll
        for (int ct = 0; ct < 4; ++ct) {
            pool[ct] += __shfl_xor(pool[ct], 16, 64);
            pool[ct] += __shfl_xor(pool[ct], 32, 64);
        }
        if ((t & 63) < 16) {
            #pragma unroll
            for (int ct = 0; ct < 4; ++ct)
                wpool[w * 64 + ct * 16 + l15] = pool[ct];
        }
    }
    __syncthreads();

    // ---- final pool over 16 waves + project MLP ----
    if (t < 64) {
        float s = 0.0f;
        #pragma unroll
        for (int w = 0; w < 16; ++w) s += wpool[w * 64 + t];
        gvec[t] = s * (1.0f / 1024.0f);
    }
    __syncthreads();

    if (t < 128) {
        float s = bp[t];
        #pragma unroll
        for (int f = 0; f < 64; ++f) s += gvec[f] * Wp[f * 128 + t];
        s = fmaxf(s, NEG * s);
        out[(size_t)b * 128 + t] = s;
    }
}

// =====================================================================
extern "C" void kernel_launch(void* const* d_in, const int* in_sizes, int n_in,
                              void* d_out, int out_size, void* d_ws, size_t ws_size,
                              hipStream_t stream) {
    const float* x  = (const float*)d_in[0];
    const int*   ei = (const int*)  d_in[1];
    const float* W1 = (const float*)d_in[2];
    const float* b1 = (const float*)d_in[3];
    const float* W2 = (const float*)d_in[4];
    const float* b2 = (const float*)d_in[5];
    const float* Wp = (const float*)d_in[6];
    const float* bp = (const float*)d_in[7];
    float* out = (float*)d_out;

    char* ws = (char*)d_ws;
    int*   rowptr = (int*)  (ws + ROWPTR_OFF);
    int2*  colw   = (int2*) (ws + COLW_OFF);
    float* selfw  = (float*)(ws + SELFW_OFF);
    int*   perm   = (int*)  (ws + PERM_OFF);

    build_csr<<<1, 1024, 0, stream>>>(ei, rowptr, colw, selfw, perm);

    (void)hipFuncSetAttribute((const void*)gnn_main,
                              hipFuncAttributeMaxDynamicSharedMemorySize, SM_TOTAL);
    gnn_main<<<NBATCH, 1024, SM_TOTAL, stream>>>(
        x, rowptr, colw, selfw, perm, W1, b1, W2, b2, Wp, bp, out);
}

// Round 4
// 40.893 us; speedup vs baseline: 6.6548x; 1.0678x over previous
//
#include <hip/hip_runtime.h>

#define N_ATOMS 1024
#define N_EDGES 8192
#define EPAD    (N_EDGES + N_ATOMS)   // padded edge capacity (even per-atom lists)
#define NBATCH  256
#define NEG     0.01f

typedef unsigned int u32;
typedef __attribute__((ext_vector_type(2))) float f32x2;
typedef __attribute__((ext_vector_type(4))) float f32x4;
typedef __attribute__((ext_vector_type(8))) short bf16x8;

// 2×f32 -> packed bf16 (RNE), 1 instruction (m214-verified on gfx950)
__device__ __forceinline__ u32 cvtpk(float lo, float hi) {
    u32 r;
    asm("v_cvt_pk_bf16_f32 %0, %1, %2" : "=v"(r) : "v"(lo), "v"(hi));
    return r;
}
// packed bf16 pair -> 2×f32
__device__ __forceinline__ f32x2 bfpair(u32 u) {
    f32x2 h;
    h.x = __uint_as_float(u << 16);
    h.y = __uint_as_float(u & 0xffff0000u);
    return h;
}

// ---------- workspace layout ----------
#define ROWPTR_OFF 0                   // int[1025] (pad 4352)
#define COLW_OFF   4352                // int2[EPAD] = 73728
#define SELFW_OFF  (4352 + 73728)      // float[1024]
#define PERM_OFF   (SELFW_OFF + 4096)  // int[1024]
#define W2T_OFF    (PERM_OFF + 4096)   // u32[2048] bf16-pair W2^T = 8192 B

// ---------- LDS layout of main kernel ----------
#define TSTR_B 144                            // tile row stride bytes (72 bf16)
#define SM_TILE_BYTES (N_ATOMS * TSTR_B)      // 147456
#define SM_CT_OFF SM_TILE_BYTES               // ctile: 1024*3 f32 = 12288 B
#define SM_TOTAL (SM_TILE_BYTES + 12288)      // 159744 <= 163840

// =====================================================================
// Kernel 1: CSR (dst-grouped, even-padded lists) + norm weights +
// degree-sorted permutation + W2^T bf16. 1 block, amortized.
// =====================================================================
__global__ __launch_bounds__(1024) void build_csr(
    const int* __restrict__ ei,
    int*  __restrict__ rowptr,
    int2* __restrict__ colw,
    float* __restrict__ selfw_g,
    int*  __restrict__ perm_g,
    u32*  __restrict__ w2t,
    const float* __restrict__ W2)
{
    __shared__ int   sdeg[N_ATOMS];
    __shared__ int   sstart[N_ATOMS];
    __shared__ float sdinv[N_ATOMS];
    __shared__ int   wtot[16];
    __shared__ int   hist[128];
    const int t = threadIdx.x;
    const int lane = t & 63;
    const int w = t >> 6;
    const int* srcA = ei;
    const int* dstA = ei + N_EDGES;

    sdeg[t] = 0;
    if (t < 128) hist[t] = 0;
    // zero padded colw capacity (pad slots stay {src=0, w=0})
    for (int e = t; e < EPAD; e += 1024) colw[e] = make_int2(0, 0);
    __syncthreads();
    for (int e = t; e < N_EDGES; e += 1024) atomicAdd(&sdeg[dstA[e]], 1);
    __syncthreads();

    const int deg  = sdeg[t];
    const int pdeg = (deg + 1) & ~1;          // even-padded length
    // wave-level inclusive scan of pdeg
    int v = pdeg;
    #pragma unroll
    for (int d = 1; d < 64; d <<= 1) {
        int u = __shfl_up(v, d, 64);
        if (lane >= d) v += u;
    }
    if (lane == 63) wtot[w] = v;
    __syncthreads();
    if (t == 0) {
        int run = 0;
        #pragma unroll
        for (int i = 0; i < 16; ++i) { int c = wtot[i]; wtot[i] = run; run += c; }
    }
    __syncthreads();
    const int start = v - pdeg + wtot[w];     // even ✓ (all pdeg even)
    sstart[t] = start;
    const float dv = rsqrtf((float)deg + 1.0f);
    sdinv[t] = dv;
    rowptr[t] = start;
    if (t == N_ATOMS - 1) rowptr[N_ATOMS] = start + pdeg;
    selfw_g[t] = dv * dv;

    // W2^T in bf16 pairs: w2t[c*32+kk] = pack(W2[2kk][c], W2[2kk+1][c])
    #pragma unroll
    for (int i = 0; i < 2; ++i) {
        const int idx = t + i * 1024;
        const int c = idx >> 5, kk = idx & 31;
        w2t[c * 32 + kk] = cvtpk(W2[(2 * kk) * 64 + c], W2[(2 * kk + 1) * 64 + c]);
    }

    // degree histogram -> counting-sort permutation
    const int dcl = deg < 127 ? deg : 127;
    atomicAdd(&hist[dcl], 1);
    sdeg[t] = 0;   // reuse as fill counters
    __syncthreads();
    if (t == 0) {
        int run = 0;
        for (int i = 0; i < 128; ++i) { int c = hist[i]; hist[i] = run; run += c; }
    }
    __syncthreads();
    const int pos = atomicAdd(&hist[dcl], 1);
    perm_g[pos] = t;
    __syncthreads();

    for (int e = t; e < N_EDGES; e += 1024) {
        const int d = dstA[e];
        const int s = srcA[e];
        const int slot = atomicAdd(&sdeg[d], 1);
        const float wgt = sdinv[s] * sdinv[d];
        colw[sstart[d] + slot] = make_int2(s, __float_as_int(wgt));
    }
}

// =====================================================================
// Kernel 2: fused GCN x2 + mean-pool + project. 1 block per molecule.
// 1024 threads, 1 atom/thread (degree-sorted). GEMM2 via MFMA.
// =====================================================================
__global__ __launch_bounds__(1024, 4) void gnn_main(
    const float* __restrict__ x,
    const int*  __restrict__ rowptr,
    const int2* __restrict__ colw,
    const float* __restrict__ selfw_g,
    const int*  __restrict__ perm_g,
    const float* __restrict__ W1, const float* __restrict__ b1,
    const u32*  __restrict__ w2t, const float* __restrict__ b2,
    const float* __restrict__ Wp, const float* __restrict__ bp,
    float* __restrict__ out)
{
    extern __shared__ char smem[];
    float* ctile = (float*)(smem + SM_CT_OFF);   // [1024*3] coords (phase 0/1)
    float* wpool = ctile;                        // aliased post-gather: [16][64]
    float* gvec  = ctile + 1024;                 // [64]
    float* proj  = ctile + 1152;                 // [4][128]

    const int t = threadIdx.x;
    const int b = blockIdx.x;
    const float* xb = x + (size_t)b * (3 * N_ATOMS);

    const int atom = perm_g[t];
    const int s0 = rowptr[atom], s1 = rowptr[atom + 1];
    const float sw = selfw_g[atom];

    // ---- phase 0: coords -> ctile (coalesced linear copy) ----
    #pragma unroll
    for (int i = 0; i < 3; ++i) ctile[t + i * 1024] = xb[t + i * 1024];
    __syncthreads();

    // ---- phase 1: aggregate coords, GEMM1 + leaky -> bf16 tile (keep pw) ----
    u32 pw[32];
    {
        const float* crs = ctile + atom * 3;
        float A0 = sw * crs[0], A1 = sw * crs[1], A2 = sw * crs[2];
        for (int j = s0; j < s1; j += 2) {
            const int4 cw = *(const int4*)(colw + j);   // 2 edges, 16B aligned
            const float* c0 = ctile + cw.x * 3;
            const float* c1 = ctile + cw.z * 3;
            const float w0 = __int_as_float(cw.y), w1 = __int_as_float(cw.w);
            A0 += w0 * c0[0] + w1 * c1[0];
            A1 += w0 * c0[1] + w1 * c1[1];
            A2 += w0 * c0[2] + w1 * c1[2];
        }
        #pragma unroll
        for (int p = 0; p < 32; ++p) {
            f32x2 vv = *(const f32x2*)(b1 + 2 * p);
            vv = __builtin_elementwise_fma((f32x2){A0, A0}, *(const f32x2*)(W1 + 2 * p), vv);
            vv = __builtin_elementwise_fma((f32x2){A1, A1}, *(const f32x2*)(W1 + 64 + 2 * p), vv);
            vv = __builtin_elementwise_fma((f32x2){A2, A2}, *(const f32x2*)(W1 + 128 + 2 * p), vv);
            vv.x = fmaxf(vv.x, NEG * vv.x);
            vv.y = fmaxf(vv.y, NEG * vv.y);
            pw[p] = cvtpk(vv.x, vv.y);
        }
        uint4* trow = (uint4*)(smem + (size_t)atom * TSTR_B);
        #pragma unroll
        for (int q = 0; q < 8; ++q)
            trow[q] = make_uint4(pw[4 * q], pw[4 * q + 1], pw[4 * q + 2], pw[4 * q + 3]);
    }
    __syncthreads();

    // ---- phase 2: gather h1 over edges; acc = f32x2[32] (pk_fma) ----
    f32x2 acc[32];
    {
        const f32x2 sw2 = {sw, sw};   // self term from registers (no LDS reads)
        #pragma unroll
        for (int p = 0; p < 32; ++p) acc[p] = bfpair(pw[p]) * sw2;
        for (int j = s0; j < s1; j += 2) {
            const int4 cw = *(const int4*)(colw + j);
            const uint4* rA = (const uint4*)(smem + (size_t)cw.x * TSTR_B);
            const uint4* rB = (const uint4*)(smem + (size_t)cw.z * TSTR_B);
            const f32x2 wA = {__int_as_float(cw.y), __int_as_float(cw.y)};
            const f32x2 wB = {__int_as_float(cw.w), __int_as_float(cw.w)};
            #pragma unroll
            for (int m = 0; m < 8; ++m) {
                const uint4 qA = rA[m];
                acc[4*m+0] = __builtin_elementwise_fma(bfpair(qA.x), wA, acc[4*m+0]);
                acc[4*m+1] = __builtin_elementwise_fma(bfpair(qA.y), wA, acc[4*m+1]);
                acc[4*m+2] = __builtin_elementwise_fma(bfpair(qA.z), wA, acc[4*m+2]);
                acc[4*m+3] = __builtin_elementwise_fma(bfpair(qA.w), wA, acc[4*m+3]);
                const uint4 qB = rB[m];
                acc[4*m+0] = __builtin_elementwise_fma(bfpair(qB.x), wB, acc[4*m+0]);
                acc[4*m+1] = __builtin_elementwise_fma(bfpair(qB.y), wB, acc[4*m+1]);
                acc[4*m+2] = __builtin_elementwise_fma(bfpair(qB.z), wB, acc[4*m+2]);
                acc[4*m+3] = __builtin_elementwise_fma(bfpair(qB.w), wB, acc[4*m+3]);
            }
        }
    }
    __syncthreads();   // ALL gathers done -> safe to overwrite tile

    // writeback own agg row (bf16)
    {
        u32 pb[32];
        #pragma unroll
        for (int p = 0; p < 32; ++p) pb[p] = cvtpk(acc[p].x, acc[p].y);
        uint4* trow = (uint4*)(smem + (size_t)atom * TSTR_B);
        #pragma unroll
        for (int q = 0; q < 8; ++q)
            trow[q] = make_uint4(pb[4 * q], pb[4 * q + 1], pb[4 * q + 2], pb[4 * q + 3]);
    }

    // ---- phase 3 (no barrier: each wave reads only its own lanes' rows) ----
    {
        const int l15 = t & 15;
        const int lq  = (t & 63) >> 4;
        const int w   = t >> 6;

        bf16x8 wf[2][4];
        #pragma unroll
        for (int kt = 0; kt < 2; ++kt)
            #pragma unroll
            for (int ct = 0; ct < 4; ++ct)
                wf[kt][ct] = *(const bf16x8*)(w2t + (ct * 16 + l15) * 32 + kt * 16 + lq * 4);
        float bias[4];
        #pragma unroll
        for (int ct = 0; ct < 4; ++ct) bias[ct] = b2[ct * 16 + l15];

        float pool[4] = {0.f, 0.f, 0.f, 0.f};
        #pragma unroll
        for (int rt = 0; rt < 4; ++rt) {
            const int arow = __shfl(atom, rt * 16 + l15, 64);   // own-wave row
            const char* ab = smem + (size_t)arow * TSTR_B + lq * 16;
            const bf16x8 a0 = *(const bf16x8*)(ab);
            const bf16x8 a1 = *(const bf16x8*)(ab + 64);
            #pragma unroll
            for (int ct = 0; ct < 4; ++ct) {
                f32x4 cf = {0.f, 0.f, 0.f, 0.f};
                cf = __builtin_amdgcn_mfma_f32_16x16x32_bf16(a0, wf[0][ct], cf, 0, 0, 0);
                cf = __builtin_amdgcn_mfma_f32_16x16x32_bf16(a1, wf[1][ct], cf, 0, 0, 0);
                float s = 0.0f;
                #pragma unroll
                for (int r = 0; r < 4; ++r) {
                    const float vv = cf[r] + bias[ct];
                    s += fmaxf(vv, NEG * vv);
                }
                pool[ct] += s;
            }
        }
        #pragma unroll
        for (int ct = 0; ct < 4; ++ct) {
            pool[ct] += __shfl_xor(pool[ct], 16, 64);
            pool[ct] += __shfl_xor(pool[ct], 32, 64);
        }
        if ((t & 63) < 16) {
            #pragma unroll
            for (int ct = 0; ct < 4; ++ct)
                wpool[w * 64 + ct * 16 + l15] = pool[ct];
        }
    }
    __syncthreads();

    // ---- final pool + project (split over 512 threads) ----
    if (t < 64) {
        float s = 0.0f;
        #pragma unroll
        for (int w = 0; w < 16; ++w) s += wpool[w * 64 + t];
        gvec[t] = s * (1.0f / 1024.0f);
    }
    __syncthreads();
    if (t < 512) {
        const int col = t & 127, pc = t >> 7;
        float s = 0.0f;
        #pragma unroll
        for (int f = 0; f < 16; ++f)
            s += gvec[pc * 16 + f] * Wp[(pc * 16 + f) * 128 + col];
        proj[pc * 128 + col] = s;
    }
    __syncthreads();
    if (t < 128) {
        float s = bp[t] + proj[t] + proj[128 + t] + proj[256 + t] + proj[384 + t];
        s = fmaxf(s, NEG * s);
        out[(size_t)b * 128 + t] = s;
    }
}

// =====================================================================
extern "C" void kernel_launch(void* const* d_in, const int* in_sizes, int n_in,
                              void* d_out, int out_size, void* d_ws, size_t ws_size,
                              hipStream_t stream) {
    const float* x  = (const float*)d_in[0];
    const int*   ei = (const int*)  d_in[1];
    const float* W1 = (const float*)d_in[2];
    const float* b1 = (const float*)d_in[3];
    const float* W2 = (const float*)d_in[4];
    const float* b2 = (const float*)d_in[5];
    const float* Wp = (const float*)d_in[6];
    const float* bp = (const float*)d_in[7];
    float* out = (float*)d_out;

    char* ws = (char*)d_ws;
    int*   rowptr = (int*)  (ws + ROWPTR_OFF);
    int2*  colw   = (int2*) (ws + COLW_OFF);
    float* selfw  = (float*)(ws + SELFW_OFF);
    int*   perm   = (int*)  (ws + PERM_OFF);
    u32*   w2t    = (u32*)  (ws + W2T_OFF);

    build_csr<<<1, 1024, 0, stream>>>(ei, rowptr, colw, selfw, perm, w2t, W2);

    (void)hipFuncSetAttribute((const void*)gnn_main,
                              hipFuncAttributeMaxDynamicSharedMemorySize, SM_TOTAL);
    gnn_main<<<NBATCH, 1024, SM_TOTAL, stream>>>(
        x, rowptr, colw, selfw, perm, W1, b1, w2t, b2, Wp, bp, out);
}

// Round 5
// 39.282 us; speedup vs baseline: 6.9277x; 1.0410x over previous
//
#include <hip/hip_runtime.h>

#define N_ATOMS 1024
#define N_EDGES 8192
#define EPAD    (N_EDGES + N_ATOMS)   // padded edge capacity (even per-atom lists)
#define NBATCH  256
#define NEG     0.01f

typedef unsigned int u32;
typedef __attribute__((ext_vector_type(2))) float f32x2;
typedef __attribute__((ext_vector_type(4))) float f32x4;
typedef __attribute__((ext_vector_type(8))) _Float16 f16x8;

// pack 2×f32 -> 2×f16 (RTZ), 1 instruction
__device__ __forceinline__ u32 pkrtz(float lo, float hi) {
    u32 r;
    asm("v_cvt_pkrtz_f16_f32 %0, %1, %2" : "=v"(r) : "v"(lo), "v"(hi));
    return r;
}
// acc += w * f16(lo half of u)   /   hi half — single VOP3P v_fma_mix_f32
#define FMIX_LO(a, w, u) \
    asm("v_fma_mix_f32 %0, %1, %2, %0 op_sel_hi:[0,1,0]" : "+v"(a) : "v"(w), "v"(u))
#define FMIX_HI(a, w, u) \
    asm("v_fma_mix_f32 %0, %1, %2, %0 op_sel:[0,1,0] op_sel_hi:[0,1,0]" : "+v"(a) : "v"(w), "v"(u))

// ---------- workspace layout ----------
#define ROWPTR_OFF 0                   // int[1025] (pad 4352)
#define COLW_OFF   4352                // int2[EPAD] = 73728
#define SELFW_OFF  (4352 + 73728)      // float[1024]
#define PERM_OFF   (SELFW_OFF + 4096)  // int[1024]
#define W2T_OFF    (PERM_OFF + 4096)   // u32[2048] f16-pair W2^T = 8192 B

// ---------- LDS layout of main kernel ----------
#define TSTR_B 144                            // tile row stride bytes (64 f16 + pad)
#define SM_TILE_BYTES (N_ATOMS * TSTR_B)      // 147456
#define SM_CT_OFF SM_TILE_BYTES               // ctile4: 1024 float4 = 16384 B
#define SM_TOTAL (SM_TILE_BYTES + 16384)      // 163840 == 160 KiB exactly

// =====================================================================
// Kernel 1: CSR (dst-grouped, even-padded lists) + norm weights +
// degree-sorted permutation + W2^T fp16. 1 block, amortized.
// =====================================================================
__global__ __launch_bounds__(1024) void build_csr(
    const int* __restrict__ ei,
    int*  __restrict__ rowptr,
    int2* __restrict__ colw,
    float* __restrict__ selfw_g,
    int*  __restrict__ perm_g,
    u32*  __restrict__ w2t,
    const float* __restrict__ W2)
{
    __shared__ int   sdeg[N_ATOMS];
    __shared__ int   sstart[N_ATOMS];
    __shared__ float sdinv[N_ATOMS];
    __shared__ int   wtot[16];
    __shared__ int   hist[128];
    const int t = threadIdx.x;
    const int lane = t & 63;
    const int w = t >> 6;
    const int* srcA = ei;
    const int* dstA = ei + N_EDGES;

    sdeg[t] = 0;
    if (t < 128) hist[t] = 0;
    for (int e = t; e < EPAD; e += 1024) colw[e] = make_int2(0, 0);
    __syncthreads();
    for (int e = t; e < N_EDGES; e += 1024) atomicAdd(&sdeg[dstA[e]], 1);
    __syncthreads();

    const int deg  = sdeg[t];
    const int pdeg = (deg + 1) & ~1;          // even-padded length
    int v = pdeg;
    #pragma unroll
    for (int d = 1; d < 64; d <<= 1) {
        int u = __shfl_up(v, d, 64);
        if (lane >= d) v += u;
    }
    if (lane == 63) wtot[w] = v;
    __syncthreads();
    if (t == 0) {
        int run = 0;
        #pragma unroll
        for (int i = 0; i < 16; ++i) { int c = wtot[i]; wtot[i] = run; run += c; }
    }
    __syncthreads();
    const int start = v - pdeg + wtot[w];     // even (all pdeg even)
    sstart[t] = start;
    const float dv = rsqrtf((float)deg + 1.0f);
    sdinv[t] = dv;
    rowptr[t] = start;
    if (t == N_ATOMS - 1) rowptr[N_ATOMS] = start + pdeg;
    selfw_g[t] = dv * dv;

    // W2^T in f16 pairs: w2t[c*32+kk] = pkrtz(W2[2kk][c], W2[2kk+1][c])
    #pragma unroll
    for (int i = 0; i < 2; ++i) {
        const int idx = t + i * 1024;
        const int c = idx >> 5, kk = idx & 31;
        w2t[c * 32 + kk] = pkrtz(W2[(2 * kk) * 64 + c], W2[(2 * kk + 1) * 64 + c]);
    }

    // degree histogram -> counting-sort permutation
    const int dcl = deg < 127 ? deg : 127;
    atomicAdd(&hist[dcl], 1);
    sdeg[t] = 0;   // reuse as fill counters
    __syncthreads();
    if (t == 0) {
        int run = 0;
        for (int i = 0; i < 128; ++i) { int c = hist[i]; hist[i] = run; run += c; }
    }
    __syncthreads();
    const int pos = atomicAdd(&hist[dcl], 1);
    perm_g[pos] = t;
    __syncthreads();

    for (int e = t; e < N_EDGES; e += 1024) {
        const int d = dstA[e];
        const int s = srcA[e];
        const int slot = atomicAdd(&sdeg[d], 1);
        const float wgt = sdinv[s] * sdinv[d];
        colw[sstart[d] + slot] = make_int2(s, __float_as_int(wgt));
    }
}

// =====================================================================
// Kernel 2: fused GCN x2 + mean-pool + project. 1 block per molecule.
// 1024 threads, 1 atom/thread (degree-sorted). fp16 tile + fma_mix.
// =====================================================================
__global__ __launch_bounds__(1024, 4) void gnn_main(
    const float* __restrict__ x,
    const int*  __restrict__ rowptr,
    const int2* __restrict__ colw,
    const float* __restrict__ selfw_g,
    const int*  __restrict__ perm_g,
    const float* __restrict__ W1, const float* __restrict__ b1,
    const u32*  __restrict__ w2t, const float* __restrict__ b2,
    const float* __restrict__ Wp, const float* __restrict__ bp,
    float* __restrict__ out)
{
    extern __shared__ char smem[];
    float4* ctile4 = (float4*)(smem + SM_CT_OFF);  // [1024] coords xyz_ (ph 0/1)
    float*  paux   = (float*)ctile4;               // aliased post-phase-1:
    float*  wpool  = paux;                         //   [16][64]
    float*  gvec   = paux + 1024;                  //   [64]
    float*  proj   = paux + 1088;                  //   [4][128]

    const int t = threadIdx.x;
    const int b = blockIdx.x;
    const float* xb = x + (size_t)b * (3 * N_ATOMS);

    const int atom = perm_g[t];
    const int s0 = rowptr[atom], s1 = rowptr[atom + 1];
    const float sw = selfw_g[atom];

    // ---- phase 0: coords -> ctile4 ----
    {
        float4 c;
        c.x = xb[3 * t]; c.y = xb[3 * t + 1]; c.z = xb[3 * t + 2]; c.w = 0.0f;
        ctile4[t] = c;
    }
    __syncthreads();

    // ---- phase 1: aggregate coords, GEMM1 + leaky -> fp16 tile (keep pw) ----
    u32 pw[32];
    {
        const float4 cs = ctile4[atom];
        float A0 = sw * cs.x, A1 = sw * cs.y, A2 = sw * cs.z;
        int4 cur = make_int4(0, 0, 0, 0);
        if (s0 < s1) cur = *(const int4*)(colw + s0);
        for (int j = s0; j < s1; j += 2) {
            const int jn = (j + 2 < s1) ? (j + 2) : s0;
            const int4 nxt = *(const int4*)(colw + jn);    // prefetch
            const float4 c0 = ctile4[cur.x];
            const float4 c1 = ctile4[cur.z];
            const float w0 = __int_as_float(cur.y), w1 = __int_as_float(cur.w);
            A0 += w0 * c0.x + w1 * c1.x;
            A1 += w0 * c0.y + w1 * c1.y;
            A2 += w0 * c0.z + w1 * c1.z;
            cur = nxt;
        }
        #pragma unroll
        for (int p = 0; p < 32; ++p) {
            f32x2 vv = *(const f32x2*)(b1 + 2 * p);
            vv = __builtin_elementwise_fma((f32x2){A0, A0}, *(const f32x2*)(W1 + 2 * p), vv);
            vv = __builtin_elementwise_fma((f32x2){A1, A1}, *(const f32x2*)(W1 + 64 + 2 * p), vv);
            vv = __builtin_elementwise_fma((f32x2){A2, A2}, *(const f32x2*)(W1 + 128 + 2 * p), vv);
            vv.x = fmaxf(vv.x, NEG * vv.x);
            vv.y = fmaxf(vv.y, NEG * vv.y);
            pw[p] = pkrtz(vv.x, vv.y);
        }
        uint4* trow = (uint4*)(smem + (size_t)atom * TSTR_B);
        #pragma unroll
        for (int q = 0; q < 8; ++q)
            trow[q] = make_uint4(pw[4 * q], pw[4 * q + 1], pw[4 * q + 2], pw[4 * q + 3]);
    }
    __syncthreads();

    // ---- phase 2: gather h1 over edges; 1 v_fma_mix per feature ----
    float acc[64];
    {
        #pragma unroll
        for (int f = 0; f < 64; ++f) acc[f] = 0.0f;
        // self term from registers
        #pragma unroll
        for (int p = 0; p < 32; ++p) {
            FMIX_LO(acc[2 * p],     sw, pw[p]);
            FMIX_HI(acc[2 * p + 1], sw, pw[p]);
        }
        int4 cur = make_int4(0, 0, 0, 0);
        if (s0 < s1) cur = *(const int4*)(colw + s0);
        for (int j = s0; j < s1; j += 2) {
            const int jn = (j + 2 < s1) ? (j + 2) : s0;
            const int4 nxt = *(const int4*)(colw + jn);    // prefetch
            const uint4* rA = (const uint4*)(smem + (size_t)cur.x * TSTR_B);
            const uint4* rB = (const uint4*)(smem + (size_t)cur.z * TSTR_B);
            const float wA = __int_as_float(cur.y);
            const float wB = __int_as_float(cur.w);
            #pragma unroll
            for (int m = 0; m < 8; ++m) {
                const uint4 qA = rA[m];
                FMIX_LO(acc[8*m+0], wA, qA.x); FMIX_HI(acc[8*m+1], wA, qA.x);
                FMIX_LO(acc[8*m+2], wA, qA.y); FMIX_HI(acc[8*m+3], wA, qA.y);
                FMIX_LO(acc[8*m+4], wA, qA.z); FMIX_HI(acc[8*m+5], wA, qA.z);
                FMIX_LO(acc[8*m+6], wA, qA.w); FMIX_HI(acc[8*m+7], wA, qA.w);
            }
            #pragma unroll
            for (int m = 0; m < 8; ++m) {
                const uint4 qB = rB[m];
                FMIX_LO(acc[8*m+0], wB, qB.x); FMIX_HI(acc[8*m+1], wB, qB.x);
                FMIX_LO(acc[8*m+2], wB, qB.y); FMIX_HI(acc[8*m+3], wB, qB.y);
                FMIX_LO(acc[8*m+4], wB, qB.z); FMIX_HI(acc[8*m+5], wB, qB.z);
                FMIX_LO(acc[8*m+6], wB, qB.w); FMIX_HI(acc[8*m+7], wB, qB.w);
            }
            cur = nxt;
        }
    }
    __syncthreads();   // ALL gathers done -> safe to overwrite tile

    // writeback own agg row (fp16)
    {
        u32 pb[32];
        #pragma unroll
        for (int p = 0; p < 32; ++p) pb[p] = pkrtz(acc[2 * p], acc[2 * p + 1]);
        uint4* trow = (uint4*)(smem + (size_t)atom * TSTR_B);
        #pragma unroll
        for (int q = 0; q < 8; ++q)
            trow[q] = make_uint4(pb[4 * q], pb[4 * q + 1], pb[4 * q + 2], pb[4 * q + 3]);
    }

    // ---- phase 3: GEMM2 via MFMA f16 (no barrier: own-wave rows only) ----
    {
        const int l15 = t & 15;
        const int lq  = (t & 63) >> 4;
        const int w   = t >> 6;

        f16x8 wf[2][4];
        #pragma unroll
        for (int kt = 0; kt < 2; ++kt)
            #pragma unroll
            for (int ct = 0; ct < 4; ++ct)
                wf[kt][ct] = *(const f16x8*)(w2t + (ct * 16 + l15) * 32 + kt * 16 + lq * 4);
        float bias[4];
        #pragma unroll
        for (int ct = 0; ct < 4; ++ct) bias[ct] = b2[ct * 16 + l15];

        float pool[4] = {0.f, 0.f, 0.f, 0.f};
        #pragma unroll
        for (int rt = 0; rt < 4; ++rt) {
            const int arow = __shfl(atom, rt * 16 + l15, 64);   // own-wave row
            const char* ab = smem + (size_t)arow * TSTR_B + lq * 16;
            const f16x8 a0 = *(const f16x8*)(ab);
            const f16x8 a1 = *(const f16x8*)(ab + 64);
            #pragma unroll
            for (int ct = 0; ct < 4; ++ct) {
                f32x4 cf = {0.f, 0.f, 0.f, 0.f};
                cf = __builtin_amdgcn_mfma_f32_16x16x32_f16(a0, wf[0][ct], cf, 0, 0, 0);
                cf = __builtin_amdgcn_mfma_f32_16x16x32_f16(a1, wf[1][ct], cf, 0, 0, 0);
                float s = 0.0f;
                #pragma unroll
                for (int r = 0; r < 4; ++r) {
                    const float vv = cf[r] + bias[ct];
                    s += fmaxf(vv, NEG * vv);
                }
                pool[ct] += s;
            }
        }
        #pragma unroll
        for (int ct = 0; ct < 4; ++ct) {
            pool[ct] += __shfl_xor(pool[ct], 16, 64);
            pool[ct] += __shfl_xor(pool[ct], 32, 64);
        }
        if ((t & 63) < 16) {
            #pragma unroll
            for (int ct = 0; ct < 4; ++ct)
                wpool[w * 64 + ct * 16 + l15] = pool[ct];
        }
    }
    __syncthreads();

    // ---- final pool + project ----
    if (t < 64) {
        float s = 0.0f;
        #pragma unroll
        for (int w = 0; w < 16; ++w) s += wpool[w * 64 + t];
        gvec[t] = s * (1.0f / 1024.0f);
    }
    __syncthreads();
    if (t < 512) {
        const int col = t & 127, pc = t >> 7;
        float s = 0.0f;
        #pragma unroll
        for (int f = 0; f < 16; ++f)
            s += gvec[pc * 16 + f] * Wp[(pc * 16 + f) * 128 + col];
        proj[pc * 128 + col] = s;
    }
    __syncthreads();
    if (t < 128) {
        float s = bp[t] + proj[t] + proj[128 + t] + proj[256 + t] + proj[384 + t];
        s = fmaxf(s, NEG * s);
        out[(size_t)b * 128 + t] = s;
    }
}

// =====================================================================
extern "C" void kernel_launch(void* const* d_in, const int* in_sizes, int n_in,
                              void* d_out, int out_size, void* d_ws, size_t ws_size,
                              hipStream_t stream) {
    const float* x  = (const float*)d_in[0];
    const int*   ei = (const int*)  d_in[1];
    const float* W1 = (const float*)d_in[2];
    const float* b1 = (const float*)d_in[3];
    const float* W2 = (const float*)d_in[4];
    const float* b2 = (const float*)d_in[5];
    const float* Wp = (const float*)d_in[6];
    const float* bp = (const float*)d_in[7];
    float* out = (float*)d_out;

    char* ws = (char*)d_ws;
    int*   rowptr = (int*)  (ws + ROWPTR_OFF);
    int2*  colw   = (int2*) (ws + COLW_OFF);
    float* selfw  = (float*)(ws + SELFW_OFF);
    int*   perm   = (int*)  (ws + PERM_OFF);
    u32*   w2t    = (u32*)  (ws + W2T_OFF);

    build_csr<<<1, 1024, 0, stream>>>(ei, rowptr, colw, selfw, perm, w2t, W2);

    (void)hipFuncSetAttribute((const void*)gnn_main,
                              hipFuncAttributeMaxDynamicSharedMemorySize, SM_TOTAL);
    gnn_main<<<NBATCH, 1024, SM_TOTAL, stream>>>(
        x, rowptr, colw, selfw, perm, W1, b1, w2t, b2, Wp, bp, out);
}